// Round 5
// baseline (120.499 us; speedup 1.0000x reference)
//
#include <hip/hip_runtime.h>

// Problem: N=2048, M=512, D=128, all fp32.
// Outputs (flat): [0]=min_loss, [1]=wise_min_loss, [2..2+N*D)=z_out.
//
// SINGLE dispatch, 1024 blocks (exactly 4/CU co-resident at launch_bounds 256,4).
// Relies on documented harness behavior: d_ws is 0xAA-poisoned before every
// call. 0xAAAAAAAA as unsigned exceeds every nonneg-float bit pattern, so
// unsigned atomicMin needs no init; the completion counter's base is poison.
//
// ws layout (unsigned cells):
//   [0 .. 512)          min_sum[m]      (float bits, unsigned-min)
//   [512 .. 512+65536)  min_elem[m][d]  (float bits, unsigned-min)
//   [66048]             completion counter (base = 0xAAAAAAAA)
//
// Blocks: [0,512)=elem  [512,768)=sum  [768,1024)=mask.
// The 768th elem/sum contributor reduces the min cells -> out[0..1].
//
// R4 lesson: sum path must NOT hold the 128-float z row in registers
// (VGPR_Count=76 proved the compiler spilled it under launch_bounds(256,2)).
// Loop order here: outer d-chunk (one float4 of z live), inner 16 m's into
// s[16]; e indices are block-uniform -> s_load on the scalar pipe.

#define N_ 2048
#define M_ 512
#define D_ 128
#define ME_OFF  M_                  // 512
#define CNT_OFF (M_ + M_ * D_)      // 66048
#define POISON  0xAAAAAAAAu
#define CONTRIB 768u

__global__ void __launch_bounds__(256, 4) k_all(
        const float* __restrict__ z, const float* __restrict__ e,
        const float* __restrict__ probs, const float* __restrict__ drop,
        float* __restrict__ out, unsigned int* __restrict__ ws) {
    const int bx = blockIdx.x;
    const int t  = threadIdx.x;
    bool contrib = true;

    if (bx < 512) {
        // ---- elem: min over one 256-n chunk for 8 m's; atomicMin merge ----
        const int mg = bx >> 3, chunk = bx & 7;
        const int d = t & 127, half = t >> 7;
        const int m0 = mg * 8 + half * 4;
        const int n0 = chunk * 256;

        const float e0 = e[(m0 + 0) * D_ + d];
        const float e1 = e[(m0 + 1) * D_ + d];
        const float e2 = e[(m0 + 2) * D_ + d];
        const float e3 = e[(m0 + 3) * D_ + d];

        float me0 = __uint_as_float(0x7f800000u), me1 = me0, me2 = me0, me3 = me0;
        const float* zp = z + n0 * D_ + d;
        #pragma unroll 16
        for (int i = 0; i < 256; ++i) {
            float zv = zp[i * D_];
            float df;
            df = zv - e0; me0 = fminf(me0, df * df);
            df = zv - e1; me1 = fminf(me1, df * df);
            df = zv - e2; me2 = fminf(me2, df * df);
            df = zv - e3; me3 = fminf(me3, df * df);
        }
        unsigned int* me = ws + ME_OFF + m0 * D_ + d;
        atomicMin(me + 0 * D_, __float_as_uint(me0));
        atomicMin(me + 1 * D_, __float_as_uint(me1));
        atomicMin(me + 2 * D_, __float_as_uint(me2));
        atomicMin(me + 3 * D_, __float_as_uint(me3));
    } else if (bx < 768) {
        // ---- sum: thread owns n; outer d-chunk, inner 16 m's into s[16] ----
        const int b = bx - 512;
        const int nb = b >> 5, mt = b & 31;
        const int n = nb * 256 + t;
        const int m0 = mt * 16;

        float s[16];
        #pragma unroll
        for (int k = 0; k < 16; ++k) s[k] = 0.f;

        const float4* z4 = reinterpret_cast<const float4*>(z) + n * 32;
        const float4* e4 = reinterpret_cast<const float4*>(e) + m0 * 32;

        #pragma unroll 4
        for (int j = 0; j < 32; ++j) {
            const float4 zv = z4[j];
            #pragma unroll
            for (int k = 0; k < 16; ++k) {
                const float4 ev = e4[k * 32 + j];   // block-uniform -> s_load
                float dx = zv.x - ev.x; s[k] = fmaf(dx, dx, s[k]);
                float dy = zv.y - ev.y; s[k] = fmaf(dy, dy, s[k]);
                float dz = zv.z - ev.z; s[k] = fmaf(dz, dz, s[k]);
                float dw = zv.w - ev.w; s[k] = fmaf(dw, dw, s[k]);
            }
        }
        // 16 independent wave-min reductions (chains pipeline), then atomics.
        #pragma unroll
        for (int off = 32; off; off >>= 1) {
            #pragma unroll
            for (int k = 0; k < 16; ++k)
                s[k] = fminf(s[k], __shfl_xor(s[k], off));
        }
        if ((t & 63) == 0) {
            #pragma unroll
            for (int k = 0; k < 16; ++k)
                atomicMin(&ws[m0 + k], __float_as_uint(s[k]));
        }
    } else {
        // ---- dropout mask ----
        contrib = false;
        const int b = bx - 768;
        const int i = b * 256 + t;              // float4 index, 65536 total
        const int n = i >> 5;
        const float p = probs[n];
        const float4 zv = reinterpret_cast<const float4*>(z)[i];
        const float4 dv = reinterpret_cast<const float4*>(drop)[i];
        float2 lo, hi;
        lo.x = dv.x < p ? zv.x : 0.f;
        lo.y = dv.y < p ? zv.y : 0.f;
        hi.x = dv.z < p ? zv.z : 0.f;
        hi.y = dv.w < p ? zv.w : 0.f;
        float2* o = reinterpret_cast<float2*>(out + 2) + i * 2;
        o[0] = lo;
        o[1] = hi;
    }

    if (!contrib) return;

    // ---- completion protocol ----
    __shared__ unsigned int lastFlag;
    __syncthreads();                    // all lanes' atomics issued
    if (t == 0) {
        __threadfence();                // release: mins visible before count
        unsigned int old = atomicAdd(ws + CNT_OFF, 1u);
        lastFlag = (old == POISON + (CONTRIB - 1u)) | (old == CONTRIB - 1u);
    }
    __syncthreads();
    if (!lastFlag) return;

    // ---- finisher: reduce 258KB of mins -> out[0..1] ----
    __threadfence();                    // acquire
    const float* wf = reinterpret_cast<const float*>(ws);

    float s_elem = 0.f;
    const float4* me4 = reinterpret_cast<const float4*>(wf + ME_OFF);
    #pragma unroll 8
    for (int k = 0; k < 64; ++k) {      // 16384 float4 / 256 threads
        float4 v = me4[k * 256 + t];
        s_elem += (v.x + v.y) + (v.z + v.w);
    }
    float s_sum = 0.f;
    if (t < 128) {                      // 512 floats = 128 float4
        float4 u = reinterpret_cast<const float4*>(wf)[t];
        s_sum = (u.x + u.y) + (u.z + u.w);
    }
    #pragma unroll
    for (int off = 32; off; off >>= 1) {
        s_elem += __shfl_xor(s_elem, off);
        s_sum  += __shfl_xor(s_sum, off);
    }
    __shared__ float sm[8];
    const int w = t >> 6;
    if ((t & 63) == 0) { sm[w] = s_elem; sm[4 + w] = s_sum; }
    __syncthreads();
    if (t == 0) {
        float te = sm[0] + sm[1] + sm[2] + sm[3];
        float ts = sm[4] + sm[5] + sm[6] + sm[7];
        out[0] = ts * (1.0f / 512.0f);
        out[1] = te * (1.0f / 65536.0f);
    }
}

extern "C" void kernel_launch(void* const* d_in, const int* in_sizes, int n_in,
                              void* d_out, int out_size, void* d_ws, size_t ws_size,
                              hipStream_t stream) {
    const float* z     = (const float*)d_in[0];
    const float* e     = (const float*)d_in[1];
    const float* probs = (const float*)d_in[2];
    const float* drop  = (const float*)d_in[3];
    float* out = (float*)d_out;
    unsigned int* ws = (unsigned int*)d_ws;

    k_all<<<dim3(1024), dim3(256), 0, stream>>>(z, e, probs, drop, out, ws);
}

// Round 6
// 91.239 us; speedup vs baseline: 1.3207x; 1.3207x over previous
//
#include <hip/hip_runtime.h>

// Problem: N=2048, M=512, D=128, all fp32.
// Outputs (flat): [0]=min_loss, [1]=wise_min_loss, [2..2+N*D)=z_out.
//
// R6: back to the proven R3 2-dispatch skeleton (87.5us, best) with fixes:
//  - sum path: d-chunked register tiling (zq[8] live, 4-way acc chains),
//    z read exactly once; e as wave-uniform broadcast loads (NOT scalar pipe
//    — R5 proved the s_load version serializes).
//  - elem path: 8 m's/thread -> half the z loads, 24 VALU/load.
//  - launch_bounds(256,4): both paths <128 VGPR -> 16 waves/CU (R3 had 8).
//
// k_main: 768 blocks: [0,256)=elem  [256,512)=sum  [512,768)=mask.
// k_fin:  64 blocks: min-reduce partials -> means -> out[0..1].
//
// ws layout (floats):
//   [0 .. 524288)        pb_elem[chunk][m][d]   (8*512*128, 2MB)
//   [524288 .. 540672)   pb_sum[m][32]          (512*32)
//   [540672 .. +2)       acc[2]
//   [540674]             counter (uint, zeroed by mask block 0)

#define N_ 2048
#define M_ 512
#define D_ 128
#define PB_SUM  (8 * M_ * D_)          // 524288
#define ACC_OFF (PB_SUM + M_ * 32)     // 540672
#define CNT_OFF (ACC_OFF + 2)

__global__ void __launch_bounds__(256, 4) k_main(
        const float* __restrict__ z, const float* __restrict__ e,
        const float* __restrict__ probs, const float* __restrict__ drop,
        float* __restrict__ out, float* __restrict__ ws) {
    const int bx = blockIdx.x;
    const int t  = threadIdx.x;

    if (bx < 256) {
        // ---- elem partials: min over one 256-n chunk for 16 m's ----
        // thread: d = t&127, half -> 8 m's in registers, plain store.
        const int mg = bx >> 3, chunk = bx & 7;
        const int d = t & 127, half = t >> 7;
        const int m0 = mg * 16 + half * 8;
        const int n0 = chunk * 256;

        float ev[8], mn[8];
        #pragma unroll
        for (int k = 0; k < 8; ++k) {
            ev[k] = e[(m0 + k) * D_ + d];
            mn[k] = __uint_as_float(0x7f800000u);
        }
        const float* zp = z + n0 * D_ + d;
        #pragma unroll 8
        for (int i = 0; i < 256; ++i) {
            float zv = zp[i * D_];
            #pragma unroll
            for (int k = 0; k < 8; ++k) {
                float df = zv - ev[k];
                mn[k] = fminf(mn[k], df * df);
            }
        }
        float* pe = ws + (size_t)chunk * (M_ * D_) + m0 * D_ + d;
        #pragma unroll
        for (int k = 0; k < 8; ++k) pe[k * D_] = mn[k];
    } else if (bx < 512) {
        // ---- sum partials: thread owns n; d in 4 chunks of 8 float4 ----
        const int b = bx - 256;
        const int nb = b >> 5, mt = b & 31;
        const int n = nb * 256 + t;
        const int m0 = mt * 16;

        float s[16];
        #pragma unroll
        for (int k = 0; k < 16; ++k) s[k] = 0.f;

        const float4* z4 = reinterpret_cast<const float4*>(z) + n * 32;
        const float4* e4 = reinterpret_cast<const float4*>(e);

        #pragma unroll 1
        for (int dc = 0; dc < 4; ++dc) {
            float4 zq[8];
            #pragma unroll
            for (int jj = 0; jj < 8; ++jj) zq[jj] = z4[dc * 8 + jj];
            #pragma unroll
            for (int k = 0; k < 16; ++k) {
                const float4* ep = e4 + (m0 + k) * 32 + dc * 8;
                float a0 = 0.f, a1 = 0.f, a2 = 0.f, a3 = 0.f;
                #pragma unroll
                for (int jj = 0; jj < 8; ++jj) {
                    float4 evq = ep[jj];            // wave-uniform broadcast
                    float dx = zq[jj].x - evq.x; a0 = fmaf(dx, dx, a0);
                    float dy = zq[jj].y - evq.y; a1 = fmaf(dy, dy, a1);
                    float dz = zq[jj].z - evq.z; a2 = fmaf(dz, dz, a2);
                    float dw = zq[jj].w - evq.w; a3 = fmaf(dw, dw, a3);
                }
                s[k] += (a0 + a1) + (a2 + a3);
            }
        }
        // 16 independent wave-min reductions, then one store per (m, wave).
        #pragma unroll
        for (int off = 32; off; off >>= 1) {
            #pragma unroll
            for (int k = 0; k < 16; ++k)
                s[k] = fminf(s[k], __shfl_xor(s[k], off));
        }
        if ((t & 63) == 0) {
            const int w = t >> 6;
            #pragma unroll
            for (int k = 0; k < 16; ++k)
                ws[PB_SUM + (m0 + k) * 32 + nb * 4 + w] = s[k];
        }
    } else {
        // ---- dropout mask; block 512 zeroes acc/counter for k_fin ----
        const int b = bx - 512;
        const int i = b * 256 + t;              // float4 index, 65536 total
        const int n = i >> 5;
        const float p = probs[n];
        const float4 zv = reinterpret_cast<const float4*>(z)[i];
        const float4 dv = reinterpret_cast<const float4*>(drop)[i];
        float2 lo, hi;
        lo.x = dv.x < p ? zv.x : 0.f;
        lo.y = dv.y < p ? zv.y : 0.f;
        hi.x = dv.z < p ? zv.z : 0.f;
        hi.y = dv.w < p ? zv.w : 0.f;
        float2* o = reinterpret_cast<float2*>(out + 2) + i * 2;
        o[0] = lo;
        o[1] = hi;
        if (b == 0 && t == 0) {
            ws[ACC_OFF] = 0.f;
            ws[ACC_OFF + 1] = 0.f;
            reinterpret_cast<unsigned int*>(ws)[CNT_OFF] = 0u;
        }
    }
}

__device__ __forceinline__ float min4(float4 v) {
    return fminf(fminf(v.x, v.y), fminf(v.z, v.w));
}

__global__ void __launch_bounds__(256) k_fin(float* __restrict__ ws,
                                             float* __restrict__ out) {
    const int b = blockIdx.x, t = threadIdx.x;
    float* acc = ws + ACC_OFF;
    unsigned int* cnt = reinterpret_cast<unsigned int*>(ws) + CNT_OFF;

    // elem: min over 8 chunks of 4 cells, then local sum
    const int cell = b * 1024 + t * 4;
    float4 mv = *reinterpret_cast<const float4*>(ws + cell);
    #pragma unroll
    for (int c = 1; c < 8; ++c) {
        float4 v = *reinterpret_cast<const float4*>(ws + c * (M_ * D_) + cell);
        mv.x = fminf(mv.x, v.x); mv.y = fminf(mv.y, v.y);
        mv.z = fminf(mv.z, v.z); mv.w = fminf(mv.w, v.w);
    }
    float s_elem = (mv.x + mv.y) + (mv.z + mv.w);

    // sum path: m in [b*8, b*8+8), 8 lanes per m cover 32 partials
    float s_sum = 0.f;
    if (t < 64) {
        const int m = b * 8 + (t >> 3);
        const int j = t & 7;
        float4 v = *reinterpret_cast<const float4*>(ws + PB_SUM + m * 32 + j * 4);
        float mn = min4(v);
        mn = fminf(mn, __shfl_xor(mn, 1));
        mn = fminf(mn, __shfl_xor(mn, 2));
        mn = fminf(mn, __shfl_xor(mn, 4));
        if ((t & 7) == 0) s_sum = mn;
    }

    #pragma unroll
    for (int off = 32; off; off >>= 1) {
        s_elem += __shfl_xor(s_elem, off);
        s_sum  += __shfl_xor(s_sum, off);
    }
    __shared__ float sm[8];
    const int w = t >> 6;
    if ((t & 63) == 0) { sm[w] = s_elem; sm[4 + w] = s_sum; }
    __syncthreads();
    if (t == 0) {
        float te = sm[0] + sm[1] + sm[2] + sm[3];
        float ts = sm[4] + sm[5] + sm[6] + sm[7];
        atomicAdd(&acc[0], ts);
        atomicAdd(&acc[1], te);
        __threadfence();
        unsigned int old = atomicAdd(cnt, 1u);
        if (old == 63u) {
            float a0 = atomicAdd(&acc[0], 0.f);   // RMW read: coherent
            float a1 = atomicAdd(&acc[1], 0.f);
            out[0] = a0 * (1.0f / 512.0f);
            out[1] = a1 * (1.0f / 65536.0f);
        }
    }
}

extern "C" void kernel_launch(void* const* d_in, const int* in_sizes, int n_in,
                              void* d_out, int out_size, void* d_ws, size_t ws_size,
                              hipStream_t stream) {
    const float* z     = (const float*)d_in[0];
    const float* e     = (const float*)d_in[1];
    const float* probs = (const float*)d_in[2];
    const float* drop  = (const float*)d_in[3];
    float* out = (float*)d_out;
    float* ws  = (float*)d_ws;

    k_main<<<dim3(768), dim3(256), 0, stream>>>(z, e, probs, drop, out, ws);
    k_fin<<<dim3(64), dim3(256), 0, stream>>>(ws, out);
}